// Round 9
// baseline (95.584 us; speedup 1.0000x reference)
//
#include <hip/hip_runtime.h>

typedef _Float16 f16;
typedef _Float16 f16x8 __attribute__((ext_vector_type(8)));
typedef _Float16 f16x4 __attribute__((ext_vector_type(4)));
typedef float f32x4 __attribute__((ext_vector_type(4)));

#define MFMA16(a, b, c) __builtin_amdgcn_mfma_f32_16x16x32_f16(a, b, c, 0, 0, 0)

constexpr int Bn = 8, Sn = 2048, En = 1024, Hn = 64;
constexpr int Mn = Bn * Sn;  // 16384
constexpr float QSCALE = 11.5415603f;  // 8 * log2(e): softmax in exp2 domain
constexpr float THR = 11.5f;           // defer-max threshold (log2 domain)

__device__ __forceinline__ void gload_lds16(const void* g, void* lds) {
    __builtin_amdgcn_global_load_lds(
        (const __attribute__((address_space(1))) void*)g,
        (__attribute__((address_space(3))) void*)lds, 16, 0, 0);
}
__device__ __forceinline__ void barrier_raw() {
    __builtin_amdgcn_s_barrier();
    __builtin_amdgcn_sched_barrier(0);
}

// ---------------------------------------------------------------------------
// Kernel 0: one-time W fp32 -> fp16 repack into per-set K-major slices.
// Wc layout: [set][row 0..63][chunk 0..127] where chunk = 8 halves of k;
// chunk stored at c ^ (row & 7) (XOR involution) so proj's linear
// global_load_lds image + XOR-on-read ds_read_b128 is bank-conflict-free.
// set 0 = Wq, 1 = Wk, 2 = Wv.
// ---------------------------------------------------------------------------
__global__ __launch_bounds__(256) void convw_kernel(
    const float* __restrict__ Wq, const float* __restrict__ Wk,
    const float* __restrict__ Wv, f16* __restrict__ Wc)
{
    const int h = blockIdx.x * 256 + threadIdx.x;  // 0..24575, one 16-B chunk
    const int set = h >> 13;
    const int rem = h & 8191;
    const int row = rem >> 7;
    const int c = rem & 127;
    const float* src = (set == 0 ? Wq : (set == 1 ? Wk : Wv))
                       + (size_t)row * En + c * 8;
    float4 v0 = *reinterpret_cast<const float4*>(src);
    float4 v1 = *reinterpret_cast<const float4*>(src + 4);
    f16x8 o = {(f16)v0.x, (f16)v0.y, (f16)v0.z, (f16)v0.w,
               (f16)v1.x, (f16)v1.y, (f16)v1.z, (f16)v1.w};
    const int cs = c ^ (row & 7);
    *reinterpret_cast<f16x8*>(
        Wc + (size_t)set * 65536 + row * 1024 + cs * 8) = o;
}

// ---------------------------------------------------------------------------
// Kernel 1: QKV projection, LDS-resident W-slice, barrier-free k-loop.
// WG = (mchunk 0..255, nset 0..2); 512 thr (8 waves: rt=w&3 row-tile,
// nh=w>>2 n-half). W-slice 64x1024 f16 = 128 KB staged ONCE via
// global_load_lds; then 32 fully-unrolled BK=32 steps of
// {x dwordx4 loads (4-deep rotating prefetch) + cvt + 2 ds_read_b128 + 2
// MFMA} with NO barriers. Q scaled by QSCALE; V^T stored kappa-reordered.
// ---------------------------------------------------------------------------
__global__ __launch_bounds__(512) void proj_kernel(
    const float* __restrict__ x, const f16* __restrict__ Wc,
    const float* __restrict__ bq, const float* __restrict__ bk,
    const float* __restrict__ bv,
    f16* __restrict__ qws, f16* __restrict__ kws, f16* __restrict__ vtws)
{
    __shared__ f16 Wlds[65536];  // 64 rows x 1024 k (128 KB), chunk-swizzled
    const int tid = threadIdx.x;
    const int w = tid >> 6, l = tid & 63;
    const int l15 = l & 15, lhi = l >> 4;
    const int rt = w & 3, nh = w >> 2;
    const int wg = blockIdx.x;
    const int nset = wg % 3;
    const int Mbase = (wg / 3) * 64;
    char* ldsb = reinterpret_cast<char*>(Wlds);

    // ---- stage W-slice once: 16 rounds x 512 thr x 16 B = 128 KB ----
    const f16* wsl = Wc + (size_t)nset * 65536;
#pragma unroll
    for (int r = 0; r < 16; ++r)
        gload_lds16(wsl + r * 4096 + w * 512 + l * 8,
                    ldsb + r * 8192 + w * 1024);

    // ---- x prefetch (4-deep rotating slots), issued before the drain ----
    const float* xrow = x + (size_t)(Mbase + rt * 16 + l15) * En;
    float4 xa[4][2];
#define XL(slot, kk)                                                          \
    {                                                                         \
        const float* p_ = xrow + (kk) * 32 + lhi * 8;                         \
        xa[slot][0] = *reinterpret_cast<const float4*>(p_);                   \
        xa[slot][1] = *reinterpret_cast<const float4*>(p_ + 4);               \
    }
    XL(0, 0) XL(1, 1) XL(2, 2) XL(3, 3)
    // 16 stage-gloads are the oldest of 24 outstanding; drain them only.
    asm volatile("s_waitcnt vmcnt(8)" ::: "memory");
    __builtin_amdgcn_sched_barrier(0);
    barrier_raw();  // all waves' stripes staged; LDS read-only hereafter

    f32x4 acc[2];
    acc[0] = (f32x4){0.f, 0.f, 0.f, 0.f};
    acc[1] = (f32x4){0.f, 0.f, 0.f, 0.f};
    const int row0 = nh * 32 + l15;      // B-frag rows (within W-slice)
    const int row1 = row0 + 16;
    const int rx = row0 & 7;             // == row1 & 7

#pragma unroll
    for (int k = 0; k < 32; ++k) {
        const int slot = k & 3;
        f16x8 a = (f16x8){
            (f16)xa[slot][0].x, (f16)xa[slot][0].y,
            (f16)xa[slot][0].z, (f16)xa[slot][0].w,
            (f16)xa[slot][1].x, (f16)xa[slot][1].y,
            (f16)xa[slot][1].z, (f16)xa[slot][1].w};
        if (k + 4 < 32) XL(slot, k + 4)
        const int ch = (k * 4 + lhi) ^ rx;
        f16x8 b0 = *reinterpret_cast<const f16x8*>(ldsb + row0 * 2048 + ch * 16);
        f16x8 b1 = *reinterpret_cast<const f16x8*>(ldsb + row1 * 2048 + ch * 16);
        acc[0] = MFMA16(a, b0, acc[0]);
        acc[1] = MFMA16(a, b1, acc[1]);
    }
#undef XL

    // ---- epilogue ----
    const float* bias_p = (nset == 0 ? bq : (nset == 1 ? bk : bv));
    const int batch = Mbase >> 11;
    const int r0 = Mbase + rt * 16 + lhi * 4;
#pragma unroll
    for (int nt = 0; nt < 2; ++nt) {
        const int h = nh * 32 + nt * 16 + l15;
        const float bias = bias_p[h];
        if (nset == 0) {
#pragma unroll
            for (int r = 0; r < 4; ++r)
                qws[(size_t)(r0 + r) * Hn + h] =
                    (f16)((acc[nt][r] + bias) * QSCALE);
        } else if (nset == 1) {
#pragma unroll
            for (int r = 0; r < 4; ++r)
                kws[(size_t)(r0 + r) * Hn + h] = (f16)(acc[nt][r] + bias);
        } else {
            const int s0 = r0 & (Sn - 1);
            const int sp = (s0 & ~31) + ((s0 & 12) << 1)
                         + ((s0 & 16) ? 4 : 0);  // kappa-reorder
            f16x4 hv = {(f16)(acc[nt][0] + bias), (f16)(acc[nt][1] + bias),
                        (f16)(acc[nt][2] + bias), (f16)(acc[nt][3] + bias)};
            *reinterpret_cast<f16x4*>(
                &vtws[(size_t)batch * Hn * Sn + (size_t)h * Sn + sp]) = hv;
        }
    }
}

// ---------------------------------------------------------------------------
// Kernel 2: causal flash attention (unchanged from round 7/8).
// ---------------------------------------------------------------------------
__global__ __launch_bounds__(256, 3) void attn_kernel(
    const f16* __restrict__ qws, const f16* __restrict__ kws,
    const f16* __restrict__ vtws, float* __restrict__ out,
    float* __restrict__ slots)
{
    const int tid = threadIdx.x;
    const int w = tid >> 6, l = tid & 63;
    const int l15 = l & 15, lhi = l >> 4;

    const int L = blockIdx.x * 4 + w;
    const int u = (int)(((unsigned)L * 997u) % 2304u);
    const int b = u / 288;
    const int t = u - b * 288;
    int k = 0;
#pragma unroll
    for (int gg = 1; gg < 8; ++gg)
        if (t >= 4 * gg * (gg + 1)) k = gg;
    const int rem = t - 4 * k * (k + 1);
    const int jq = rem / (k + 1);
    const int c = rem - jq * (k + 1);
    const int J = 8 * k + jq;

    const int qbase = J * 32;
    const int nkt = J + 1;
    const int ts = c * 8;
    const int te = (ts + 8 < nkt) ? ts + 8 : nkt;
    const bool hasDiag = (te == nkt);
    const int nfull = te - (hasDiag ? 1 : 0);

    const f16* qb = qws + (size_t)b * Sn * Hn;
    const f16* kb = kws + (size_t)b * Sn * Hn;
    const f16* vtb = vtws + (size_t)b * Hn * Sn;

    f16x8 qf[2][2];
#pragma unroll
    for (int rs = 0; rs < 2; ++rs)
#pragma unroll
        for (int kc = 0; kc < 2; ++kc)
            qf[rs][kc] = *reinterpret_cast<const f16x8*>(
                &qb[(size_t)(qbase + rs * 16 + l15) * Hn + kc * 32 + lhi * 8]);

    f32x4 O[2][4];
#pragma unroll
    for (int rs = 0; rs < 2; ++rs)
#pragma unroll
        for (int nt = 0; nt < 4; ++nt) O[rs][nt] = (f32x4){0.f, 0.f, 0.f, 0.f};
    float m1[2] = {-1e30f, -1e30f}, l1[2] = {0.f, 0.f};

#define ATTN_ITER(KT, MASKED)                                                 \
    {                                                                         \
        const int kbase = (KT) * 32;                                          \
        f16x8 kf[2][2];                                                       \
        _Pragma("unroll") for (int nt = 0; nt < 2; ++nt)                      \
        _Pragma("unroll") for (int kc = 0; kc < 2; ++kc)                      \
            kf[nt][kc] = *reinterpret_cast<const f16x8*>(                     \
                &kb[(size_t)(kbase + nt * 16 + l15) * Hn + kc * 32            \
                    + lhi * 8]);                                              \
        f32x4 Sv[2][2];                                                       \
        _Pragma("unroll") for (int rs = 0; rs < 2; ++rs)                      \
        _Pragma("unroll") for (int nt = 0; nt < 2; ++nt) {                    \
            f32x4 sa = (f32x4){0.f, 0.f, 0.f, 0.f};                           \
            sa = MFMA16(kf[nt][0], qf[rs][0], sa);                            \
            sa = MFMA16(kf[nt][1], qf[rs][1], sa);                            \
            Sv[rs][nt] = sa;                                                  \
        }                                                                     \
        float tv[2][2][4];                                                    \
        float mx[2];                                                          \
        _Pragma("unroll") for (int rs = 0; rs < 2; ++rs) {                    \
            _Pragma("unroll") for (int nt = 0; nt < 2; ++nt)                  \
            _Pragma("unroll") for (int r = 0; r < 4; ++r) {                   \
                float v = Sv[rs][nt][r];                                      \
                if (MASKED) {                                                 \
                    const int key_ = nt * 16 + lhi * 4 + r;                   \
                    const int qq_ = rs * 16 + l15;                            \
                    v = (key_ <= qq_) ? v : -1e30f;                           \
                }                                                             \
                tv[rs][nt][r] = v;                                            \
            }                                                                 \
            float a0 = fmaxf(fmaxf(tv[rs][0][0], tv[rs][0][1]),               \
                             fmaxf(tv[rs][0][2], tv[rs][0][3]));              \
            float a1 = fmaxf(fmaxf(tv[rs][1][0], tv[rs][1][1]),               \
                             fmaxf(tv[rs][1][2], tv[rs][1][3]));              \
            float m_ = fmaxf(a0, a1);                                         \
            m_ = fmaxf(m_, __shfl_xor(m_, 16));                               \
            m_ = fmaxf(m_, __shfl_xor(m_, 32));                               \
            mx[rs] = m_;                                                      \
        }                                                                     \
        const int need = (mx[0] > m1[0] + THR) || (mx[1] > m1[1] + THR);      \
        if (__any(need)) {                                                    \
            _Pragma("unroll") for (int rs = 0; rs < 2; ++rs) {                \
                const float mn = fmaxf(m1[rs], mx[rs]);                       \
                const float al = exp2f(m1[rs] - mn);                          \
                l1[rs] *= al;                                                 \
                _Pragma("unroll") for (int nt = 0; nt < 4; ++nt)              \
                _Pragma("unroll") for (int r = 0; r < 4; ++r)                 \
                    O[rs][nt][r] *= al;                                       \
                m1[rs] = mn;                                                  \
            }                                                                 \
        }                                                                     \
        f16x8 pa[2];                                                          \
        _Pragma("unroll") for (int rs = 0; rs < 2; ++rs) {                    \
            float p_[8];                                                      \
            float s_ = 0.f;                                                   \
            _Pragma("unroll") for (int nt = 0; nt < 2; ++nt)                  \
            _Pragma("unroll") for (int r = 0; r < 4; ++r) {                   \
                const float e_ = exp2f(tv[rs][nt][r] - m1[rs]);               \
                p_[nt * 4 + r] = e_;                                          \
                s_ += e_;                                                     \
            }                                                                 \
            s_ += __shfl_xor(s_, 16);                                         \
            s_ += __shfl_xor(s_, 32);                                         \
            l1[rs] += s_;                                                     \
            pa[rs] = (f16x8){(f16)p_[0], (f16)p_[1], (f16)p_[2], (f16)p_[3],  \
                             (f16)p_[4], (f16)p_[5], (f16)p_[6], (f16)p_[7]}; \
        }                                                                     \
        _Pragma("unroll") for (int nt = 0; nt < 4; ++nt) {                    \
            f16x8 vf = *reinterpret_cast<const f16x8*>(                       \
                &vtb[(size_t)(nt * 16 + l15) * Sn + kbase + lhi * 8]);        \
            O[0][nt] = MFMA16(vf, pa[0], O[0][nt]);                           \
            O[1][nt] = MFMA16(vf, pa[1], O[1][nt]);                           \
        }                                                                     \
    }

    for (int kt = ts; kt < nfull; ++kt) ATTN_ITER(kt, false);
    if (hasDiag) ATTN_ITER(J, true);
#undef ATTN_ITER

    if (J < 8) {
#pragma unroll
        for (int rs = 0; rs < 2; ++rs) {
            const float inv = 1.0f / l1[rs];
            const size_t ro = ((size_t)b * Sn + qbase + rs * 16 + l15) * Hn;
#pragma unroll
            for (int nt = 0; nt < 4; ++nt) {
                float4 o = {O[rs][nt][0] * inv, O[rs][nt][1] * inv,
                            O[rs][nt][2] * inv, O[rs][nt][3] * inv};
                *reinterpret_cast<float4*>(&out[ro + nt * 16 + lhi * 4]) = o;
            }
        }
    } else {
        float* sl = slots + (size_t)(b * 280 + 4 * k * (k + 1) - 8
                                     + jq * (k + 1) + c) * 1088;
        f16* so = reinterpret_cast<f16*>(sl + 64);
#pragma unroll
        for (int rs = 0; rs < 2; ++rs) {
            const int row = rs * 16 + l15;
            const float inv = 1.0f / l1[rs];
            if (lhi == 0) { sl[row] = m1[rs]; sl[32 + row] = l1[rs]; }
#pragma unroll
            for (int nt = 0; nt < 4; ++nt) {
                f16x4 hv = {(f16)(O[rs][nt][0] * inv), (f16)(O[rs][nt][1] * inv),
                            (f16)(O[rs][nt][2] * inv), (f16)(O[rs][nt][3] * inv)};
                *reinterpret_cast<f16x4*>(
                    &so[row * 64 + nt * 16 + lhi * 4]) = hv;
            }
        }
    }
}

// ---------------------------------------------------------------------------
// Kernel 3: merge chunk partials for q-blocks J>=8 (unchanged).
// ---------------------------------------------------------------------------
__global__ __launch_bounds__(256) void comb_kernel(
    const float* __restrict__ slots, float* __restrict__ out)
{
    const int id = blockIdx.x;
    const int b = id / 56, jj = id - b * 56;
    const int J = 8 + jj;
    const int k = J >> 3;
    const int nch = k + 1;
    const float* base = slots + (size_t)(b * 280 + 4 * k * (k + 1) - 8
                                         + (J - 8 * k) * (k + 1)) * 1088;
    const int tid = threadIdx.x;
    const int row = tid >> 3;
    const int h0 = (tid & 7) * 8;

    float mg = -1e30f;
    for (int cc = 0; cc < nch; ++cc)
        mg = fmaxf(mg, base[cc * 1088 + row]);
    float den = 0.f;
    float num[8] = {0.f, 0.f, 0.f, 0.f, 0.f, 0.f, 0.f, 0.f};
    for (int cc = 0; cc < nch; ++cc) {
        const float* sl = base + cc * 1088;
        const float wgt = sl[32 + row] * exp2f(sl[row] - mg);
        den += wgt;
        const f16* so = reinterpret_cast<const f16*>(sl + 64);
        f16x8 ov = *reinterpret_cast<const f16x8*>(&so[row * 64 + h0]);
#pragma unroll
        for (int i = 0; i < 8; ++i) num[i] += (float)ov[i] * wgt;
    }
    const float inv = 1.0f / den;
    const size_t ro = ((size_t)b * Sn + J * 32 + row) * Hn + h0;
    float4 o0 = {num[0] * inv, num[1] * inv, num[2] * inv, num[3] * inv};
    float4 o1 = {num[4] * inv, num[5] * inv, num[6] * inv, num[7] * inv};
    *reinterpret_cast<float4*>(&out[ro]) = o0;
    *reinterpret_cast<float4*>(&out[ro + 4]) = o1;
}

// ---------------------------------------------------------------------------
extern "C" void kernel_launch(void* const* d_in, const int* in_sizes, int n_in,
                              void* d_out, int out_size, void* d_ws, size_t ws_size,
                              hipStream_t stream) {
    const float* x  = (const float*)d_in[0];
    const float* Wk = (const float*)d_in[1];
    const float* bk = (const float*)d_in[2];
    const float* Wq = (const float*)d_in[3];
    const float* bq = (const float*)d_in[4];
    const float* Wv = (const float*)d_in[5];
    const float* bv = (const float*)d_in[6];

    f16* qws  = (f16*)d_ws;                    // 2 MB (Q pre-scaled by QSCALE)
    f16* kws  = qws + (size_t)Mn * Hn;         // 2 MB
    f16* vtws = kws + (size_t)Mn * Hn;         // 2 MB (kappa-ordered V^T)
    f16* Wc   = vtws + (size_t)Mn * Hn;        // 384 KB (per-set, swizzled)
    float* slots = (float*)(Wc + 196608);      // 2240 * 1088 f32 (~9.75 MB)

    convw_kernel<<<96, 256, 0, stream>>>(Wq, Wk, Wv, Wc);
    proj_kernel<<<768, 512, 0, stream>>>(x, Wc, bq, bk, bv, qws, kws, vtws);
    attn_kernel<<<576, 256, 0, stream>>>(qws, kws, vtws, (float*)d_out, slots);
    comb_kernel<<<448, 256, 0, stream>>>(slots, (float*)d_out);
}

// Round 10
// 73.262 us; speedup vs baseline: 1.3047x; 1.3047x over previous
//
#include <hip/hip_runtime.h>

typedef _Float16 f16;
typedef _Float16 f16x8 __attribute__((ext_vector_type(8)));
typedef _Float16 f16x4 __attribute__((ext_vector_type(4)));
typedef float f32x4 __attribute__((ext_vector_type(4)));

#define MFMA16(a, b, c) __builtin_amdgcn_mfma_f32_16x16x32_f16(a, b, c, 0, 0, 0)

constexpr int Bn = 8, Sn = 2048, En = 1024, Hn = 64;
constexpr int Mn = Bn * Sn;  // 16384
constexpr float QSCALE = 11.5415603f;  // 8 * log2(e): softmax in exp2 domain
constexpr float THR = 11.5f;           // defer-max threshold (log2 domain)

__device__ __forceinline__ void gload_lds16(const void* g, void* lds) {
    __builtin_amdgcn_global_load_lds(
        (const __attribute__((address_space(1))) void*)g,
        (__attribute__((address_space(3))) void*)lds, 16, 0, 0);
}
__device__ __forceinline__ void wait_vm7() {
    asm volatile("s_waitcnt vmcnt(7)" ::: "memory");
    __builtin_amdgcn_sched_barrier(0);
}
__device__ __forceinline__ void wait_vm0() {
    asm volatile("s_waitcnt vmcnt(0)" ::: "memory");
    __builtin_amdgcn_sched_barrier(0);
}
__device__ __forceinline__ void barrier_raw() {
    __builtin_amdgcn_s_barrier();
    __builtin_amdgcn_sched_barrier(0);
}

// ---------------------------------------------------------------------------
// Kernel 0: one-time W fp32 -> fp16 repack, PRE-SWIZZLED (round-6 layout).
// Logical [kt=16][rr=192][c=64] f16; 16-B chunk stored at c ^ (rr & 7).
// ---------------------------------------------------------------------------
__global__ __launch_bounds__(256) void convw_kernel(
    const float* __restrict__ Wq, const float* __restrict__ Wk,
    const float* __restrict__ Wv, f16* __restrict__ Wc)
{
    const int h = blockIdx.x * 256 + threadIdx.x;
    const int kt = h / 1536;
    const int rem = h - kt * 1536;
    const int rr = rem >> 3;
    const int c = rem & 7;
    const int set = rr >> 6;
    const float* src = (set == 0 ? Wq : (set == 1 ? Wk : Wv))
                       + (size_t)(rr & 63) * En + kt * 64 + c * 8;
    float4 v0 = *reinterpret_cast<const float4*>(src);
    float4 v1 = *reinterpret_cast<const float4*>(src + 4);
    f16x8 o = {(f16)v0.x, (f16)v0.y, (f16)v0.z, (f16)v0.w,
               (f16)v1.x, (f16)v1.y, (f16)v1.z, (f16)v1.w};
    const int cs = c ^ (rr & 7);
    *reinterpret_cast<f16x8*>(Wc + (size_t)kt * 12288 + rr * 64 + cs * 8) = o;
}

// ---------------------------------------------------------------------------
// Kernel 1: QKV projection. EXACT round-7 structure (BM=64, grid 256, 512
// thr, W double-buffered via global_load_lds, counted vmcnt(7)) + ONE change:
// per-WG k-phase rotation KB(i) = (i + (blockIdx.x & 15)) & 15 so the chip's
// WGs read 16 different 256-B column windows of the 4-KB x rows at any
// instant (de-hotspots HBM/L2 channels). Accumulation order is commutative.
// ---------------------------------------------------------------------------
__global__ __launch_bounds__(512) void proj_kernel(
    const float* __restrict__ x, const f16* __restrict__ Wc,
    const float* __restrict__ bq, const float* __restrict__ bk,
    const float* __restrict__ bv,
    f16* __restrict__ qws, f16* __restrict__ kws, f16* __restrict__ vtws)
{
    __shared__ f16 Wlds[2 * 12288];  // 2 x [192][64] linear (48 KB)
    const int tid = threadIdx.x;
    const int w = tid >> 6, l = tid & 63;
    const int l15 = l & 15, lhi = l >> 4;
    const int rt = w & 3, nh = w >> 2;
    const int Mbase = blockIdx.x * 64;
    const int s0 = blockIdx.x & 15;  // k-phase rotation
    const float* xrow = x + (size_t)(Mbase + rt * 16 + l15) * En;
    char* ldsb = reinterpret_cast<char*>(Wlds);

    f32x4 acc[6];
#pragma unroll
    for (int i = 0; i < 6; ++i) acc[i] = (f32x4){0.f, 0.f, 0.f, 0.f};

    float4 xr[2][2][2];

#define KB(i) (((i) + s0) & 15)

#define STAGE(buf, kb)                                                        \
    {                                                                         \
        const f16* wt_ = Wc + (size_t)(kb) * 12288;                           \
        _Pragma("unroll")                                                     \
        for (int r_ = 0; r_ < 3; ++r_)                                        \
            gload_lds16(wt_ + r_ * 4096 + w * 512 + l * 8,                    \
                        ldsb + (buf) * 24576 + r_ * 8192 + w * 1024);         \
    }

#define XLOAD(slot, kb)                                                       \
    {                                                                         \
        _Pragma("unroll")                                                     \
        for (int kc_ = 0; kc_ < 2; ++kc_) {                                   \
            const float* ap_ = xrow + (kb) * 64 + kc_ * 32 + lhi * 8;         \
            xr[slot][kc_][0] = *reinterpret_cast<const float4*>(ap_);         \
            xr[slot][kc_][1] = *reinterpret_cast<const float4*>(ap_ + 4);     \
        }                                                                     \
    }

#define COMPUTE(buf, slot)                                                    \
    {                                                                         \
        f16x8 a_[2];                                                          \
        _Pragma("unroll")                                                     \
        for (int kc_ = 0; kc_ < 2; ++kc_)                                     \
            a_[kc_] = (f16x8){                                                \
                (f16)xr[slot][kc_][0].x, (f16)xr[slot][kc_][0].y,             \
                (f16)xr[slot][kc_][0].z, (f16)xr[slot][kc_][0].w,             \
                (f16)xr[slot][kc_][1].x, (f16)xr[slot][kc_][1].y,             \
                (f16)xr[slot][kc_][1].z, (f16)xr[slot][kc_][1].w};            \
        _Pragma("unroll")                                                     \
        for (int i_ = 0; i_ < 6; ++i_) {                                      \
            const int row16_ = (nh * 6 + i_) * 16 + l15;                      \
            _Pragma("unroll")                                                 \
            for (int kc_ = 0; kc_ < 2; ++kc_) {                               \
                const int addr_ = (buf) * 24576 + row16_ * 128                \
                    + ((kc_ * 64 + lhi * 16) ^ ((l15 & 7) << 4));             \
                f16x8 b_ = *reinterpret_cast<const f16x8*>(ldsb + addr_);     \
                acc[i_] = MFMA16(a_[kc_], b_, acc[i_]);                       \
            }                                                                 \
        }                                                                     \
    }

    STAGE(0, KB(0));
    XLOAD(0, KB(0));
#pragma unroll
    for (int i = 0; i < 16; ++i) {
        const int cur = i & 1;
        if (i < 15) {
            STAGE(cur ^ 1, KB(i + 1));
            XLOAD(cur ^ 1, KB(i + 1));
            wait_vm7();   // step-i's 7 loads drained; step-(i+1)'s stay in flight
        } else {
            wait_vm0();
        }
        barrier_raw();    // all waves' stage of buf[cur] complete
        COMPUTE(cur, cur);
        barrier_raw();    // all waves done reading buf[cur] before restage
    }
#undef KB
#undef STAGE
#undef XLOAD
#undef COMPUTE

    const int batch = Mbase >> 11;
    const int r0 = Mbase + rt * 16 + lhi * 4;
#pragma unroll
    for (int i = 0; i < 6; ++i) {
        const int nt = nh * 6 + i;
        const int set = nt >> 2;
        const int h = (nt & 3) * 16 + l15;
        const float bias = (set == 0 ? bq : (set == 1 ? bk : bv))[h];
        if (set == 0) {
#pragma unroll
            for (int r = 0; r < 4; ++r)
                qws[(size_t)(r0 + r) * Hn + h] =
                    (f16)((acc[i][r] + bias) * QSCALE);
        } else if (set == 1) {
#pragma unroll
            for (int r = 0; r < 4; ++r)
                kws[(size_t)(r0 + r) * Hn + h] = (f16)(acc[i][r] + bias);
        } else {
            const int s0v = r0 & (Sn - 1);
            const int sp = (s0v & ~31) + ((s0v & 12) << 1)
                         + ((s0v & 16) ? 4 : 0);  // kappa-reorder
            f16x4 hv = {(f16)(acc[i][0] + bias), (f16)(acc[i][1] + bias),
                        (f16)(acc[i][2] + bias), (f16)(acc[i][3] + bias)};
            *reinterpret_cast<f16x4*>(
                &vtws[(size_t)batch * Hn * Sn + (size_t)h * Sn + sp]) = hv;
        }
    }
}

// ---------------------------------------------------------------------------
// Kernel 2: causal flash attention (unchanged from round 7/8/9).
// ---------------------------------------------------------------------------
__global__ __launch_bounds__(256, 3) void attn_kernel(
    const f16* __restrict__ qws, const f16* __restrict__ kws,
    const f16* __restrict__ vtws, float* __restrict__ out,
    float* __restrict__ slots)
{
    const int tid = threadIdx.x;
    const int w = tid >> 6, l = tid & 63;
    const int l15 = l & 15, lhi = l >> 4;

    const int L = blockIdx.x * 4 + w;
    const int u = (int)(((unsigned)L * 997u) % 2304u);
    const int b = u / 288;
    const int t = u - b * 288;
    int k = 0;
#pragma unroll
    for (int gg = 1; gg < 8; ++gg)
        if (t >= 4 * gg * (gg + 1)) k = gg;
    const int rem = t - 4 * k * (k + 1);
    const int jq = rem / (k + 1);
    const int c = rem - jq * (k + 1);
    const int J = 8 * k + jq;

    const int qbase = J * 32;
    const int nkt = J + 1;
    const int ts = c * 8;
    const int te = (ts + 8 < nkt) ? ts + 8 : nkt;
    const bool hasDiag = (te == nkt);
    const int nfull = te - (hasDiag ? 1 : 0);

    const f16* qb = qws + (size_t)b * Sn * Hn;
    const f16* kb = kws + (size_t)b * Sn * Hn;
    const f16* vtb = vtws + (size_t)b * Hn * Sn;

    f16x8 qf[2][2];
#pragma unroll
    for (int rs = 0; rs < 2; ++rs)
#pragma unroll
        for (int kc = 0; kc < 2; ++kc)
            qf[rs][kc] = *reinterpret_cast<const f16x8*>(
                &qb[(size_t)(qbase + rs * 16 + l15) * Hn + kc * 32 + lhi * 8]);

    f32x4 O[2][4];
#pragma unroll
    for (int rs = 0; rs < 2; ++rs)
#pragma unroll
        for (int nt = 0; nt < 4; ++nt) O[rs][nt] = (f32x4){0.f, 0.f, 0.f, 0.f};
    float m1[2] = {-1e30f, -1e30f}, l1[2] = {0.f, 0.f};

#define ATTN_ITER(KT, MASKED)                                                 \
    {                                                                         \
        const int kbase = (KT) * 32;                                          \
        f16x8 kf[2][2];                                                       \
        _Pragma("unroll") for (int nt = 0; nt < 2; ++nt)                      \
        _Pragma("unroll") for (int kc = 0; kc < 2; ++kc)                      \
            kf[nt][kc] = *reinterpret_cast<const f16x8*>(                     \
                &kb[(size_t)(kbase + nt * 16 + l15) * Hn + kc * 32            \
                    + lhi * 8]);                                              \
        f32x4 Sv[2][2];                                                       \
        _Pragma("unroll") for (int rs = 0; rs < 2; ++rs)                      \
        _Pragma("unroll") for (int nt = 0; nt < 2; ++nt) {                    \
            f32x4 sa = (f32x4){0.f, 0.f, 0.f, 0.f};                           \
            sa = MFMA16(kf[nt][0], qf[rs][0], sa);                            \
            sa = MFMA16(kf[nt][1], qf[rs][1], sa);                            \
            Sv[rs][nt] = sa;                                                  \
        }                                                                     \
        float tv[2][2][4];                                                    \
        float mx[2];                                                          \
        _Pragma("unroll") for (int rs = 0; rs < 2; ++rs) {                    \
            _Pragma("unroll") for (int nt = 0; nt < 2; ++nt)                  \
            _Pragma("unroll") for (int r = 0; r < 4; ++r) {                   \
                float v = Sv[rs][nt][r];                                      \
                if (MASKED) {                                                 \
                    const int key_ = nt * 16 + lhi * 4 + r;                   \
                    const int qq_ = rs * 16 + l15;                            \
                    v = (key_ <= qq_) ? v : -1e30f;                           \
                }                                                             \
                tv[rs][nt][r] = v;                                            \
            }                                                                 \
            float a0 = fmaxf(fmaxf(tv[rs][0][0], tv[rs][0][1]),               \
                             fmaxf(tv[rs][0][2], tv[rs][0][3]));              \
            float a1 = fmaxf(fmaxf(tv[rs][1][0], tv[rs][1][1]),               \
                             fmaxf(tv[rs][1][2], tv[rs][1][3]));              \
            float m_ = fmaxf(a0, a1);                                         \
            m_ = fmaxf(m_, __shfl_xor(m_, 16));                               \
            m_ = fmaxf(m_, __shfl_xor(m_, 32));                               \
            mx[rs] = m_;                                                      \
        }                                                                     \
        const int need = (mx[0] > m1[0] + THR) || (mx[1] > m1[1] + THR);      \
        if (__any(need)) {                                                    \
            _Pragma("unroll") for (int rs = 0; rs < 2; ++rs) {                \
                const float mn = fmaxf(m1[rs], mx[rs]);                       \
                const float al = exp2f(m1[rs] - mn);                          \
                l1[rs] *= al;                                                 \
                _Pragma("unroll") for (int nt = 0; nt < 4; ++nt)              \
                _Pragma("unroll") for (int r = 0; r < 4; ++r)                 \
                    O[rs][nt][r] *= al;                                       \
                m1[rs] = mn;                                                  \
            }                                                                 \
        }                                                                     \
        f16x8 pa[2];                                                          \
        _Pragma("unroll") for (int rs = 0; rs < 2; ++rs) {                    \
            float p_[8];                                                      \
            float s_ = 0.f;                                                   \
            _Pragma("unroll") for (int nt = 0; nt < 2; ++nt)                  \
            _Pragma("unroll") for (int r = 0; r < 4; ++r) {                   \
                const float e_ = exp2f(tv[rs][nt][r] - m1[rs]);               \
                p_[nt * 4 + r] = e_;                                          \
                s_ += e_;                                                     \
            }                                                                 \
            s_ += __shfl_xor(s_, 16);                                         \
            s_ += __shfl_xor(s_, 32);                                         \
            l1[rs] += s_;                                                     \
            pa[rs] = (f16x8){(f16)p_[0], (f16)p_[1], (f16)p_[2], (f16)p_[3],  \
                             (f16)p_[4], (f16)p_[5], (f16)p_[6], (f16)p_[7]}; \
        }                                                                     \
        _Pragma("unroll") for (int nt = 0; nt < 4; ++nt) {                    \
            f16x8 vf = *reinterpret_cast<const f16x8*>(                       \
                &vtb[(size_t)(nt * 16 + l15) * Sn + kbase + lhi * 8]);        \
            O[0][nt] = MFMA16(vf, pa[0], O[0][nt]);                           \
            O[1][nt] = MFMA16(vf, pa[1], O[1][nt]);                           \
        }                                                                     \
    }

    for (int kt = ts; kt < nfull; ++kt) ATTN_ITER(kt, false);
    if (hasDiag) ATTN_ITER(J, true);
#undef ATTN_ITER

    if (J < 8) {
#pragma unroll
        for (int rs = 0; rs < 2; ++rs) {
            const float inv = 1.0f / l1[rs];
            const size_t ro = ((size_t)b * Sn + qbase + rs * 16 + l15) * Hn;
#pragma unroll
            for (int nt = 0; nt < 4; ++nt) {
                float4 o = {O[rs][nt][0] * inv, O[rs][nt][1] * inv,
                            O[rs][nt][2] * inv, O[rs][nt][3] * inv};
                *reinterpret_cast<float4*>(&out[ro + nt * 16 + lhi * 4]) = o;
            }
        }
    } else {
        float* sl = slots + (size_t)(b * 280 + 4 * k * (k + 1) - 8
                                     + jq * (k + 1) + c) * 1088;
        f16* so = reinterpret_cast<f16*>(sl + 64);
#pragma unroll
        for (int rs = 0; rs < 2; ++rs) {
            const int row = rs * 16 + l15;
            const float inv = 1.0f / l1[rs];
            if (lhi == 0) { sl[row] = m1[rs]; sl[32 + row] = l1[rs]; }
#pragma unroll
            for (int nt = 0; nt < 4; ++nt) {
                f16x4 hv = {(f16)(O[rs][nt][0] * inv), (f16)(O[rs][nt][1] * inv),
                            (f16)(O[rs][nt][2] * inv), (f16)(O[rs][nt][3] * inv)};
                *reinterpret_cast<f16x4*>(
                    &so[row * 64 + nt * 16 + lhi * 4]) = hv;
            }
        }
    }
}

// ---------------------------------------------------------------------------
// Kernel 3: merge chunk partials for q-blocks J>=8 (unchanged).
// ---------------------------------------------------------------------------
__global__ __launch_bounds__(256) void comb_kernel(
    const float* __restrict__ slots, float* __restrict__ out)
{
    const int id = blockIdx.x;
    const int b = id / 56, jj = id - b * 56;
    const int J = 8 + jj;
    const int k = J >> 3;
    const int nch = k + 1;
    const float* base = slots + (size_t)(b * 280 + 4 * k * (k + 1) - 8
                                         + (J - 8 * k) * (k + 1)) * 1088;
    const int tid = threadIdx.x;
    const int row = tid >> 3;
    const int h0 = (tid & 7) * 8;

    float mg = -1e30f;
    for (int cc = 0; cc < nch; ++cc)
        mg = fmaxf(mg, base[cc * 1088 + row]);
    float den = 0.f;
    float num[8] = {0.f, 0.f, 0.f, 0.f, 0.f, 0.f, 0.f, 0.f};
    for (int cc = 0; cc < nch; ++cc) {
        const float* sl = base + cc * 1088;
        const float wgt = sl[32 + row] * exp2f(sl[row] - mg);
        den += wgt;
        const f16* so = reinterpret_cast<const f16*>(sl + 64);
        f16x8 ov = *reinterpret_cast<const f16x8*>(&so[row * 64 + h0]);
#pragma unroll
        for (int i = 0; i < 8; ++i) num[i] += (float)ov[i] * wgt;
    }
    const float inv = 1.0f / den;
    const size_t ro = ((size_t)b * Sn + J * 32 + row) * Hn + h0;
    float4 o0 = {num[0] * inv, num[1] * inv, num[2] * inv, num[3] * inv};
    float4 o1 = {num[4] * inv, num[5] * inv, num[6] * inv, num[7] * inv};
    *reinterpret_cast<float4*>(&out[ro]) = o0;
    *reinterpret_cast<float4*>(&out[ro + 4]) = o1;
}

// ---------------------------------------------------------------------------
extern "C" void kernel_launch(void* const* d_in, const int* in_sizes, int n_in,
                              void* d_out, int out_size, void* d_ws, size_t ws_size,
                              hipStream_t stream) {
    const float* x  = (const float*)d_in[0];
    const float* Wk = (const float*)d_in[1];
    const float* bk = (const float*)d_in[2];
    const float* Wq = (const float*)d_in[3];
    const float* bq = (const float*)d_in[4];
    const float* Wv = (const float*)d_in[5];
    const float* bv = (const float*)d_in[6];

    f16* qws  = (f16*)d_ws;                    // 2 MB (Q pre-scaled by QSCALE)
    f16* kws  = qws + (size_t)Mn * Hn;         // 2 MB
    f16* vtws = kws + (size_t)Mn * Hn;         // 2 MB (kappa-ordered V^T)
    f16* Wc   = vtws + (size_t)Mn * Hn;        // 384 KB (kt-sliced, swizzled)
    float* slots = (float*)(Wc + 196608);      // 2240 * 1088 f32 (~9.75 MB)

    convw_kernel<<<96, 256, 0, stream>>>(Wq, Wk, Wv, Wc);
    proj_kernel<<<256, 512, 0, stream>>>(x, Wc, bq, bk, bv, qws, kws, vtws);
    attn_kernel<<<576, 256, 0, stream>>>(qws, kws, vtws, (float*)d_out, slots);
    comb_kernel<<<448, 256, 0, stream>>>(slots, (float*)d_out);
}